// Round 3
// baseline (429.275 us; speedup 1.0000x reference)
//
#include <hip/hip_runtime.h>

#define G 10

typedef float vf4 __attribute__((ext_vector_type(4)));

// Force a wave-uniform loaded value into an SGPR (tables are uniform).
__device__ __forceinline__ float sload(const float* p, int i) {
    return __uint_as_float(__builtin_amdgcn_readfirstlane(__float_as_uint(p[i])));
}

__global__ __launch_bounds__(256) void madq_kernel(
    const vf4* __restrict__ x4,
    const float* __restrict__ medians,
    const float* __restrict__ deltas,
    const float* __restrict__ zps,
    vf4* __restrict__ o4,
    int n4)
{
    // 4 x vf4 (16 elements, 64 B) per thread; loads issued up front for MLP.
    const int base = blockIdx.x * (256 * 4) + threadIdx.x;

    vf4 v[4];
    bool ok[4];
#pragma unroll
    for (int j = 0; j < 4; ++j) {
        int idx = base + j * 256;
        ok[j] = idx < n4;
        if (ok[j]) v[j] = __builtin_nontemporal_load(&x4[idx]);
    }

    // Tables -> SGPRs. medians[9] is dead: the select chain only compares
    // against m[0..8] (count>=10 clamps to group 9 anyway).
    float m[G - 1], dd[G], zz[G];
#pragma unroll
    for (int i = 0; i < G - 1; ++i) m[i] = sload(medians, i);
#pragma unroll
    for (int i = 0; i < G; ++i) { dd[i] = sload(deltas, i); zz[i] = sload(zps, i); }

#pragma unroll
    for (int j = 0; j < 4; ++j) {
        if (!ok[j]) continue;
        vf4 r;
#pragma unroll
        for (int e = 0; e < 4; ++e) {
            float xv = v[j][e];
            float xa = fabsf(xv);
            // Sorted medians -> monotone select chain == table lookup by count.
            float d = dd[0], zp = zz[0];
#pragma unroll
            for (int i = 1; i < G; ++i) {
                bool c = xa >= m[i - 1];
                d  = c ? dd[i] : d;
                zp = c ? zz[i] : zp;
            }
            // rintf = round-half-even (np.round); precise IEEE div keeps absmax == 0.
            float q = rintf(xv / d) + zp;
            q = fminf(fmaxf(q, 0.0f), 255.0f);
            r[e] = (q - zp) * d;
        }
        // Output is never re-read: nontemporal store.
        __builtin_nontemporal_store(r, &o4[base + j * 256]);
    }
}

extern "C" void kernel_launch(void* const* d_in, const int* in_sizes, int n_in,
                              void* d_out, int out_size, void* d_ws, size_t ws_size,
                              hipStream_t stream) {
    const float* x       = (const float*)d_in[0];
    const float* medians = (const float*)d_in[1];
    const float* deltas  = (const float*)d_in[2];
    const float* zps     = (const float*)d_in[3];
    float*       out     = (float*)d_out;

    int n  = in_sizes[0];          // 4*4096*4096, divisible by 16
    int n4 = n / 4;                // vf4 count
    const int block = 256;
    const int per_block = block * 4;
    int grid = (n4 + per_block - 1) / per_block;
    madq_kernel<<<grid, block, 0, stream>>>(
        (const vf4*)x, medians, deltas, zps, (vf4*)out, n4);
}

// Round 4
// 425.637 us; speedup vs baseline: 1.0085x; 1.0085x over previous
//
#include <hip/hip_runtime.h>

#define G 10

typedef float vf4 __attribute__((ext_vector_type(4)));

// Force a wave-uniform loaded value into an SGPR (tables are uniform).
__device__ __forceinline__ float sload(const float* p, int i) {
    return __uint_as_float(__builtin_amdgcn_readfirstlane(__float_as_uint(p[i])));
}

__global__ __launch_bounds__(256) void madq_kernel(
    const vf4* __restrict__ x4,
    const float* __restrict__ medians,
    const float* __restrict__ deltas,
    const float* __restrict__ zps,
    vf4* __restrict__ o4,
    int n4)
{
    int idx = blockIdx.x * blockDim.x + threadIdx.x;
    if (idx >= n4) return;

    // Cached (normal) load for the read stream.
    vf4 v = x4[idx];

    // Tables -> SGPRs. medians[9] is dead: the select chain only compares
    // against m[0..8] (count>=10 clamps to group 9 anyway).
    float m[G - 1], dd[G], zz[G];
#pragma unroll
    for (int i = 0; i < G - 1; ++i) m[i] = sload(medians, i);
#pragma unroll
    for (int i = 0; i < G; ++i) { dd[i] = sload(deltas, i); zz[i] = sload(zps, i); }

    vf4 r;
#pragma unroll
    for (int e = 0; e < 4; ++e) {
        float xv = v[e];
        float xa = fabsf(xv);
        // Sorted medians -> monotone select chain == table lookup by count.
        float d = dd[0], zp = zz[0];
#pragma unroll
        for (int i = 1; i < G; ++i) {
            bool c = xa >= m[i - 1];
            d  = c ? dd[i] : d;
            zp = c ? zz[i] : zp;
        }
        // rintf = round-half-even (np.round); precise IEEE div keeps absmax == 0.
        float q = rintf(xv / d) + zp;
        q = fminf(fmaxf(q, 0.0f), 255.0f);
        r[e] = (q - zp) * d;
    }
    // Output is never re-read: nontemporal store (skip L2 write-allocate).
    __builtin_nontemporal_store(r, &o4[idx]);
}

extern "C" void kernel_launch(void* const* d_in, const int* in_sizes, int n_in,
                              void* d_out, int out_size, void* d_ws, size_t ws_size,
                              hipStream_t stream) {
    const float* x       = (const float*)d_in[0];
    const float* medians = (const float*)d_in[1];
    const float* deltas  = (const float*)d_in[2];
    const float* zps     = (const float*)d_in[3];
    float*       out     = (float*)d_out;

    int n  = in_sizes[0];          // 4*4096*4096, divisible by 4
    int n4 = n / 4;                // vf4 count
    const int block = 256;
    int grid = (n4 + block - 1) / block;
    madq_kernel<<<grid, block, 0, stream>>>(
        (const vf4*)x, medians, deltas, zps, (vf4*)out, n4);
}